// Round 2
// baseline (449.865 us; speedup 1.0000x reference)
//
#include <hip/hip_runtime.h>

typedef __attribute__((ext_vector_type(8))) short short8;
typedef __attribute__((ext_vector_type(4))) float f32x4;
typedef __attribute__((ext_vector_type(4))) unsigned short ushort4v;
typedef unsigned long long u64;

#define DM 2048
#define ND 6144
#define SEQ 2048
#define HD 128
// scale * log2(e): folded into Q weights so softmax runs in exp2 domain
#define QSCALE (0.08838834764831845f * 1.4426950408889634f)

#define MFMA(a, b, c) __builtin_amdgcn_mfma_f32_16x16x32_bf16((a), (b), (c), 0, 0, 0)

__device__ __forceinline__ unsigned short f2bf(float f) {
  unsigned int u = __float_as_uint(f);
  return (unsigned short)((u + 0x7FFFu + ((u >> 16) & 1u)) >> 16);
}
__device__ __forceinline__ float bf2f(unsigned short h) {
  return __uint_as_float(((unsigned int)h) << 16);
}

// ---------------- f32 -> bf16 bulk convert ----------------
__global__ void cvt_bf16_kernel(const float* __restrict__ src,
                                unsigned short* __restrict__ dst, int n4) {
  int i = blockIdx.x * blockDim.x + threadIdx.x;
  int st = gridDim.x * blockDim.x;
  for (; i < n4; i += st) {
    f32x4 v = ((const f32x4*)src)[i];
    ushort4v o;
    o[0] = f2bf(v[0]); o[1] = f2bf(v[1]); o[2] = f2bf(v[2]); o[3] = f2bf(v[3]);
    ((ushort4v*)dst)[i] = o;
  }
}

// ---------------- K-part of Wqkv: transpose copy into WbT rows [2048,4096) ----
__global__ void transk_kernel(const float* __restrict__ Wqkv,
                              unsigned short* __restrict__ WbT) {
  __shared__ float tile[64 * 68];
  int bx = blockIdx.x;          // 1024 = 32 dtile x 32 ctile
  int dt = bx >> 5, ct = bx & 31;
  int d0 = dt * 64, c0 = ct * 64;
  int t = threadIdx.x;
#pragma unroll
  for (int j = 0; j < 4; ++j) {
    int el = (t + j * 256) * 4;
    int r = el >> 6, cc = el & 63;
    f32x4 v = *(const f32x4*)(Wqkv + (size_t)(d0 + r) * ND + 2048 + c0 + cc);
    *(f32x4*)(&tile[r * 68 + cc]) = v;
  }
  __syncthreads();
#pragma unroll
  for (int j = 0; j < 4; ++j) {
    int el = (t + j * 256) * 4;
    int c = el >> 6, dd = el & 63;
    ushort4v o;
#pragma unroll
    for (int i = 0; i < 4; ++i) o[i] = f2bf(tile[(dd + i) * 68 + c]);
    *(ushort4v*)(&WbT[(size_t)(2048 + c0 + c) * DM + d0 + dd]) = o;
  }
}

// ---------------- fold Wq/Wv into Wqkv q/v parts -> WbT (transposed, bf16) ----
__global__ __launch_bounds__(256) void fold_kernel(const float* __restrict__ Wqkv,
                                                   const float* __restrict__ Wq,
                                                   const float* __restrict__ Wv,
                                                   unsigned short* __restrict__ WbT) {
  __shared__ float wm[128 * 64];  // [dd][e-half]   32KB
  __shared__ float wt[64 * 128];  // [d][dd]        32KB
  int bx = blockIdx.x;            // 2048 = p*1024 + head*64 + dt*2 + eh
  int p = bx >> 10;
  int head = (bx >> 6) & 15;
  int dt = (bx >> 1) & 31;
  int eh = bx & 1;
  int g = head >> 2;
  const float* Wm = (p ? Wv : Wq) + g * 16384;
  int cbase = p * 4096 + head * 128;  // column base in Wqkv (q at 0, v at 4096)
  int d0 = dt * 64;
  int t = threadIdx.x;
#pragma unroll
  for (int j = 0; j < 8; ++j) {
    int el = (t + j * 256) * 4;
    int dd = el >> 6, e = el & 63;
    *(f32x4*)(&wm[dd * 64 + e]) = *(const f32x4*)(Wm + dd * 128 + eh * 64 + e);
  }
#pragma unroll
  for (int j = 0; j < 8; ++j) {
    int el = (t + j * 256) * 4;
    int r = el >> 7, cc = el & 127;
    *(f32x4*)(&wt[r * 128 + cc]) =
        *(const f32x4*)(Wqkv + (size_t)(d0 + r) * ND + cbase + cc);
  }
  __syncthreads();
  int td = t >> 4, te = t & 15;
  int dl = td * 4, e0 = te * 4;
  float acc[4][4];
#pragma unroll
  for (int i = 0; i < 4; ++i)
#pragma unroll
    for (int j = 0; j < 4; ++j) acc[i][j] = 0.f;
  for (int dd = 0; dd < 128; ++dd) {
    f32x4 bv = *(const f32x4*)(&wm[dd * 64 + e0]);
#pragma unroll
    for (int i = 0; i < 4; ++i) {
      float a = wt[(dl + i) * 128 + dd];
#pragma unroll
      for (int j = 0; j < 4; ++j) acc[i][j] += a * bv[j];
    }
  }
  float sc = p ? 1.0f : QSCALE;
  int outcol0 = p * 4096 + head * 128 + eh * 64 + e0;
#pragma unroll
  for (int j = 0; j < 4; ++j) {
    ushort4v o;
#pragma unroll
    for (int i = 0; i < 4; ++i) o[i] = f2bf(acc[i][j] * sc);
    *(ushort4v*)(&WbT[(size_t)(outcol0 + j) * DM + d0 + dl]) = o;
  }
}

// ---------------- folded bias ----------------
__global__ void bias_kernel(const float* __restrict__ bqkv, const float* __restrict__ Wq,
                            const float* __restrict__ bq, const float* __restrict__ Wv,
                            const float* __restrict__ bv, float* __restrict__ biasf) {
  int col = blockIdx.x * 256 + threadIdx.x;
  if (col >= ND) return;
  float v;
  if (col < 2048) {
    int g = col >> 9, e = col & 127, base = col & ~127;
    float s = 0.f;
    for (int dd = 0; dd < 128; ++dd) s += bqkv[base + dd] * Wq[g * 16384 + dd * 128 + e];
    v = (s + bq[g * 128 + e]) * QSCALE;
  } else if (col < 4096) {
    v = bqkv[col];
  } else {
    int cv = col - 4096;
    int g = cv >> 9, e = cv & 127, base = col & ~127;
    float s = 0.f;
    for (int dd = 0; dd < 128; ++dd) s += bqkv[base + dd] * Wv[g * 16384 + dd * 128 + e];
    v = s + bv[g * 128 + e];
  }
  biasf[col] = v;
}

// ---------------- main GEMM: [4096,2048] x [2048,6144] bf16 (m97 structure) ----
__global__ __launch_bounds__(256) void gemm_kernel(
    const unsigned short* __restrict__ A, const unsigned short* __restrict__ Bt,
    const float* __restrict__ biasf, unsigned short* __restrict__ Qb,
    unsigned short* __restrict__ Kb, unsigned short* __restrict__ Vt) {
  __shared__ unsigned short As[128 * 32];
  __shared__ unsigned short Bs[128 * 32];
  int bid = blockIdx.x;                       // 1536
  int swz = (bid & 7) * 192 + (bid >> 3);     // XCD-aware swizzle (1536 % 8 == 0)
  int bm = swz & 31, bn = swz >> 5;
  int m0 = bm * 128, n0 = bn * 128;
  int tid = threadIdx.x, w = tid >> 6, l = tid & 63;
  int ln = l & 15, hi = l >> 4;
  int wr = w >> 1, wc = w & 1;

  int ob0 = w * 2048 + l * 16;  // byte slot in LDS tile for gload j=0
  int ob1 = ob0 + 1024;
  const unsigned short* a0 = A + (size_t)(m0 + (ob0 >> 6)) * DM + ((ob0 & 63) >> 1);
  const unsigned short* a1 = A + (size_t)(m0 + (ob1 >> 6)) * DM + ((ob1 & 63) >> 1);
  const unsigned short* b0 = Bt + (size_t)(n0 + (ob0 >> 6)) * DM + ((ob0 & 63) >> 1);
  const unsigned short* b1 = Bt + (size_t)(n0 + (ob1 >> 6)) * DM + ((ob1 & 63) >> 1);
  char* asb = (char*)(&As[0]);
  char* bsb = (char*)(&Bs[0]);

  f32x4 acc[4][4] = {};
  for (int kt = 0; kt < DM; kt += 32) {
    __syncthreads();
    __builtin_amdgcn_global_load_lds((const __attribute__((address_space(1))) void*)(a0 + kt),
                                     (__attribute__((address_space(3))) void*)(asb + w * 2048), 16, 0, 0);
    __builtin_amdgcn_global_load_lds((const __attribute__((address_space(1))) void*)(a1 + kt),
                                     (__attribute__((address_space(3))) void*)(asb + w * 2048 + 1024), 16, 0, 0);
    __builtin_amdgcn_global_load_lds((const __attribute__((address_space(1))) void*)(b0 + kt),
                                     (__attribute__((address_space(3))) void*)(bsb + w * 2048), 16, 0, 0);
    __builtin_amdgcn_global_load_lds((const __attribute__((address_space(1))) void*)(b1 + kt),
                                     (__attribute__((address_space(3))) void*)(bsb + w * 2048 + 1024), 16, 0, 0);
    __syncthreads();
    short8 af[4], bfm[4];
#pragma unroll
    for (int mi = 0; mi < 4; ++mi)
      af[mi] = *(const short8*)(&As[(wr * 64 + mi * 16 + ln) * 32 + hi * 8]);
#pragma unroll
    for (int ni = 0; ni < 4; ++ni)
      bfm[ni] = *(const short8*)(&Bs[(wc * 64 + ni * 16 + ln) * 32 + hi * 8]);
#pragma unroll
    for (int mi = 0; mi < 4; ++mi)
#pragma unroll
      for (int ni = 0; ni < 4; ++ni)
        acc[mi][ni] = MFMA(af[mi], bfm[ni], acc[mi][ni]);
  }

  int part = bn >> 4, head = bn & 15;
  int hbuf = (m0 >> 11) * 16 + head;
  int srow0 = (m0 & 2047) + wr * 64;
#pragma unroll
  for (int ni = 0; ni < 4; ++ni) {
    int col = wc * 64 + ni * 16 + ln;
    float bsv = biasf[n0 + col];
#pragma unroll
    for (int mi = 0; mi < 4; ++mi) {
      int srow = srow0 + mi * 16 + hi * 4;
      f32x4 v = acc[mi][ni];
      if (part == 2) {  // V: store transposed [head][d][s]
        ushort4v o = {f2bf(v[0] + bsv), f2bf(v[1] + bsv), f2bf(v[2] + bsv), f2bf(v[3] + bsv)};
        *(ushort4v*)(&Vt[(size_t)(hbuf * 128 + col) * SEQ + srow]) = o;
      } else {          // Q / K: [head][s][d]
        unsigned short* dst = (part ? Kb : Qb) + ((size_t)hbuf * SEQ + srow) * HD + col;
        dst[0] = f2bf(v[0] + bsv);
        dst[HD] = f2bf(v[1] + bsv);
        dst[2 * HD] = f2bf(v[2] + bsv);
        dst[3 * HD] = f2bf(v[3] + bsv);
      }
    }
  }
}

// ---------------- flash attention with post-softmax mask ----------------
__global__ __launch_bounds__(256, 2) void attn_kernel(
    const unsigned short* __restrict__ Qb, const unsigned short* __restrict__ Kb,
    const unsigned short* __restrict__ Vt, const unsigned short* __restrict__ Mb,
    float* __restrict__ out) {
  __shared__ unsigned short Ks[64 * 128];   // [key][d]   swizzled
  __shared__ unsigned short Vs[128 * 64];   // [d][key]   swizzled
  __shared__ unsigned short Ms[128 * 64];   // [q][key]   bf16 mask, swizzled
  __shared__ unsigned short Ps[4][32 * 64]; // per-wave P [q][key], swizzled
  int bx = blockIdx.x;      // 512 = hb*16 + qtile
  int hb = bx >> 4;
  int q0 = (bx & 15) * 128;
  int b = hb >> 4, head = hb & 15;
  int tid = threadIdx.x, w = tid >> 6, l = tid & 63;
  int ln = l & 15, hi = l >> 4;
  const unsigned short* Qh = Qb + ((size_t)hb * SEQ + q0 + w * 32) * HD;
  const unsigned short* Kh = Kb + (size_t)hb * SEQ * HD;
  const unsigned short* Vh = Vt + (size_t)hb * HD * SEQ;
  char* KsB = (char*)(&Ks[0]);
  char* VsB = (char*)(&Vs[0]);
  char* MsB = (char*)(&Ms[0]);
  char* PwB = (char*)(&Ps[w][0]);

  short8 qf[2][4];  // Q rows (q = qb*16+ln), pre-scaled by scale*log2e in GEMM
#pragma unroll
  for (int qb = 0; qb < 2; ++qb)
#pragma unroll
    for (int kk = 0; kk < 4; ++kk)
      qf[qb][kk] = *(const short8*)(Qh + (qb * 16 + ln) * HD + kk * 32 + hi * 8);

  f32x4 acc[8][2] = {};
  float mrun[2] = {-1e30f, -1e30f}, Zrun[2] = {0.f, 0.f};

  for (int t = 0; t < 32; ++t) {
    int k0 = t * 64;
    __syncthreads();
    {  // stage K tile [64][128]
      int row = tid >> 2, seg = (tid & 3) * 64;
      const unsigned short* src = Kh + (size_t)(k0 + row) * HD + (seg >> 1);
      short8 tv[4];
#pragma unroll
      for (int j = 0; j < 4; ++j) tv[j] = *(const short8*)(src + j * 8);
#pragma unroll
      for (int j = 0; j < 4; ++j)
        *(short8*)(KsB + ((row * 256 + seg + j * 16) ^ ((row & 7) << 4))) = tv[j];
    }
    {  // stage V^T tile [128][64]
      int row = tid >> 1, seg = (tid & 1) * 64;
      const unsigned short* src = Vh + (size_t)row * SEQ + k0 + (seg >> 1);
      short8 tv[4];
#pragma unroll
      for (int j = 0; j < 4; ++j) tv[j] = *(const short8*)(src + j * 8);
#pragma unroll
      for (int j = 0; j < 4; ++j)
        *(short8*)(VsB + ((row * 128 + seg + j * 16) ^ ((row & 7) << 4))) = tv[j];
    }
    {  // stage mask tile [128][64]
      int row = tid >> 1, seg = (tid & 1) * 64;
      const unsigned short* src = Mb + (size_t)(q0 + row) * SEQ + k0 + (seg >> 1);
      short8 tv[4];
#pragma unroll
      for (int j = 0; j < 4; ++j) tv[j] = *(const short8*)(src + j * 8);
#pragma unroll
      for (int j = 0; j < 4; ++j)
        *(short8*)(MsB + ((row * 128 + seg + j * 16) ^ ((row & 7) << 4))) = tv[j];
    }
    __syncthreads();

    // S^T = K · Q^T  (rows=key lane-local -> cheap softmax)
    f32x4 sAcc[4][2] = {};
#pragma unroll
    for (int kk = 0; kk < 4; ++kk) {
#pragma unroll
      for (int mb = 0; mb < 4; ++mb) {
        int key = mb * 16 + ln;
        short8 kf = *(const short8*)(KsB + ((key * 256 + kk * 64 + hi * 16) ^ ((key & 7) << 4)));
        sAcc[mb][0] = MFMA(kf, qf[0][kk], sAcc[mb][0]);
        sAcc[mb][1] = MFMA(kf, qf[1][kk], sAcc[mb][1]);
      }
    }

    // online softmax (exp2 domain; Z unmasked, numerator masked)
#pragma unroll
    for (int qb = 0; qb < 2; ++qb) {
      float tm = -1e30f;
#pragma unroll
      for (int mb = 0; mb < 4; ++mb)
#pragma unroll
        for (int r = 0; r < 4; ++r) tm = fmaxf(tm, sAcc[mb][qb][r]);
      tm = fmaxf(tm, __shfl_xor(tm, 16));
      tm = fmaxf(tm, __shfl_xor(tm, 32));
      float mn = fmaxf(mrun[qb], tm);
      float al = __builtin_amdgcn_exp2f(mrun[qb] - mn);
      mrun[qb] = mn;
      float ts = 0.f;
      int qrow = w * 32 + qb * 16 + ln;
      int swzm = (qrow & 7) << 4;
      int swzp = (ln & 7) << 4;
#pragma unroll
      for (int mb = 0; mb < 4; ++mb) {
        u64 mk = *(const u64*)(MsB + ((qrow * 128 + mb * 32 + hi * 8) ^ swzm));
        u64 pk = 0;
#pragma unroll
        for (int r = 0; r < 4; ++r) {
          float p = __builtin_amdgcn_exp2f(sAcc[mb][qb][r] - mn);
          ts += p;
          float pm = p * bf2f((unsigned short)(mk >> (16 * r)));
          pk |= ((u64)f2bf(pm)) << (16 * r);
        }
        *(u64*)(PwB + (((qb * 16 + ln) * 128 + mb * 32 + hi * 8) ^ swzp)) = pk;
      }
      ts += __shfl_xor(ts, 16);
      ts += __shfl_xor(ts, 32);
      Zrun[qb] = Zrun[qb] * al + ts;
#pragma unroll
      for (int db = 0; db < 8; ++db) acc[db][qb] *= al;
    }

    // out^T += V^T · P^T   (A = V^T frags, B = P row-major frags)
#pragma unroll
    for (int kv = 0; kv < 2; ++kv) {
      short8 pf[2];
#pragma unroll
      for (int qb = 0; qb < 2; ++qb)
        pf[qb] = *(const short8*)(PwB + (((qb * 16 + ln) * 128 + kv * 64 + hi * 16) ^ ((ln & 7) << 4)));
#pragma unroll
      for (int db = 0; db < 8; ++db) {
        int d = db * 16 + ln;
        short8 vf = *(const short8*)(VsB + ((d * 128 + kv * 64 + hi * 16) ^ ((d & 7) << 4)));
        acc[db][0] = MFMA(vf, pf[0], acc[db][0]);
        acc[db][1] = MFMA(vf, pf[1], acc[db][1]);
      }
    }
  }

  // epilogue: out[b][s][head*128+d] = acc/Z   (f32, coalesced 64B lines)
#pragma unroll
  for (int qb = 0; qb < 2; ++qb) {
    float rz = 1.0f / Zrun[qb];
    int srow = q0 + w * 32 + qb * 16 + ln;
    float* dst = out + ((size_t)(b * SEQ + srow)) * DM + head * HD + hi * 4;
#pragma unroll
    for (int db = 0; db < 8; ++db) {
      f32x4 o;
#pragma unroll
      for (int r = 0; r < 4; ++r) o[r] = acc[db][qb][r] * rz;
      *(f32x4*)(dst + db * 16) = o;
    }
  }
}

extern "C" void kernel_launch(void* const* d_in, const int* in_sizes, int n_in,
                              void* d_out, int out_size, void* d_ws, size_t ws_size,
                              hipStream_t stream) {
  (void)in_sizes; (void)n_in; (void)out_size; (void)ws_size;
  const float* x    = (const float*)d_in[0];
  const float* mask = (const float*)d_in[1];
  const float* Wqkv = (const float*)d_in[2];
  const float* bqkv = (const float*)d_in[3];
  const float* Wq   = (const float*)d_in[4];
  const float* bq   = (const float*)d_in[5];
  const float* Wv   = (const float*)d_in[6];
  const float* bv   = (const float*)d_in[7];
  float* out = (float*)d_out;
  char* ws = (char*)d_ws;

  unsigned short* xb    = (unsigned short*)(ws);              // 16.8 MB
  unsigned short* maskb = (unsigned short*)(ws + 16777216);   // 8.4 MB
  unsigned short* WbT   = (unsigned short*)(ws + 25165824);   // 25.2 MB
  float*          biasf = (float*)(ws + 50331648);            // 24 KB
  unsigned short* Qb    = (unsigned short*)(ws + 50356224);   // 16.8 MB
  unsigned short* Kb    = (unsigned short*)(ws + 67133440);   // 16.8 MB
  unsigned short* Vt    = (unsigned short*)(ws + 83910656);   // 16.8 MB

  cvt_bf16_kernel<<<2048, 256, 0, stream>>>(x, xb, 2097152);
  cvt_bf16_kernel<<<1024, 256, 0, stream>>>(mask, maskb, 1048576);
  transk_kernel<<<1024, 256, 0, stream>>>(Wqkv, WbT);
  fold_kernel<<<2048, 256, 0, stream>>>(Wqkv, Wq, Wv, WbT);
  bias_kernel<<<24, 256, 0, stream>>>(bqkv, Wq, bq, Wv, bv, biasf);
  gemm_kernel<<<1536, 256, 0, stream>>>(xb, WbT, biasf, Qb, Kb, Vt);
  attn_kernel<<<512, 256, 0, stream>>>(Qb, Kb, Vt, maskb, out);
}

// Round 4
// 430.935 us; speedup vs baseline: 1.0439x; 1.0439x over previous
//
#include <hip/hip_runtime.h>

typedef __attribute__((ext_vector_type(8))) short short8;
typedef __attribute__((ext_vector_type(4))) float f32x4;
typedef __attribute__((ext_vector_type(4))) unsigned short ushort4v;
typedef unsigned long long u64;

#define DM 2048
#define ND 6144
#define SEQ 2048
#define HD 128
// scale * log2(e): folded into Q weights so softmax runs in exp2 domain
#define QSCALE (0.08838834764831845f * 1.4426950408889634f)

#define MFMA(a, b, c) __builtin_amdgcn_mfma_f32_16x16x32_bf16((a), (b), (c), 0, 0, 0)

__device__ __forceinline__ unsigned short f2bf(float f) {
  unsigned int u = __float_as_uint(f);
  return (unsigned short)((u + 0x7FFFu + ((u >> 16) & 1u)) >> 16);
}
__device__ __forceinline__ float bf2f(unsigned short h) {
  return __uint_as_float(((unsigned int)h) << 16);
}

// ---------------- f32 -> bf16 bulk convert ----------------
__global__ void cvt_bf16_kernel(const float* __restrict__ src,
                                unsigned short* __restrict__ dst, int n4) {
  int i = blockIdx.x * blockDim.x + threadIdx.x;
  int st = gridDim.x * blockDim.x;
  for (; i < n4; i += st) {
    f32x4 v = ((const f32x4*)src)[i];
    ushort4v o;
    o[0] = f2bf(v[0]); o[1] = f2bf(v[1]); o[2] = f2bf(v[2]); o[3] = f2bf(v[3]);
    ((ushort4v*)dst)[i] = o;
  }
}

// ---------------- K-part of Wqkv: transpose copy into WbT rows [2048,4096) ----
__global__ void transk_kernel(const float* __restrict__ Wqkv,
                              unsigned short* __restrict__ WbT) {
  __shared__ float tile[64 * 68];
  int bx = blockIdx.x;          // 1024 = 32 dtile x 32 ctile
  int dt = bx >> 5, ct = bx & 31;
  int d0 = dt * 64, c0 = ct * 64;
  int t = threadIdx.x;
#pragma unroll
  for (int j = 0; j < 4; ++j) {
    int el = (t + j * 256) * 4;
    int r = el >> 6, cc = el & 63;
    f32x4 v = *(const f32x4*)(Wqkv + (size_t)(d0 + r) * ND + 2048 + c0 + cc);
    *(f32x4*)(&tile[r * 68 + cc]) = v;
  }
  __syncthreads();
#pragma unroll
  for (int j = 0; j < 4; ++j) {
    int el = (t + j * 256) * 4;
    int c = el >> 6, dd = el & 63;
    ushort4v o;
#pragma unroll
    for (int i = 0; i < 4; ++i) o[i] = f2bf(tile[(dd + i) * 68 + c]);
    *(ushort4v*)(&WbT[(size_t)(2048 + c0 + c) * DM + d0 + dd]) = o;
  }
}

// ---------------- fold Wq/Wv into Wqkv q/v parts -> WbT (transposed, bf16) ----
__global__ __launch_bounds__(256) void fold_kernel(const float* __restrict__ Wqkv,
                                                   const float* __restrict__ Wq,
                                                   const float* __restrict__ Wv,
                                                   unsigned short* __restrict__ WbT) {
  __shared__ float wm[128 * 64];  // [dd][e-half]   32KB
  __shared__ float wt[64 * 128];  // [d][dd]        32KB
  int bx = blockIdx.x;            // 2048 = p*1024 + head*64 + dt*2 + eh
  int p = bx >> 10;
  int head = (bx >> 6) & 15;
  int dt = (bx >> 1) & 31;
  int eh = bx & 1;
  int g = head >> 2;
  const float* Wm = (p ? Wv : Wq) + g * 16384;
  int cbase = p * 4096 + head * 128;  // column base in Wqkv (q at 0, v at 4096)
  int d0 = dt * 64;
  int t = threadIdx.x;
#pragma unroll
  for (int j = 0; j < 8; ++j) {
    int el = (t + j * 256) * 4;
    int dd = el >> 6, e = el & 63;
    *(f32x4*)(&wm[dd * 64 + e]) = *(const f32x4*)(Wm + dd * 128 + eh * 64 + e);
  }
#pragma unroll
  for (int j = 0; j < 8; ++j) {
    int el = (t + j * 256) * 4;
    int r = el >> 7, cc = el & 127;
    *(f32x4*)(&wt[r * 128 + cc]) =
        *(const f32x4*)(Wqkv + (size_t)(d0 + r) * ND + cbase + cc);
  }
  __syncthreads();
  int td = t >> 4, te = t & 15;
  int dl = td * 4, e0 = te * 4;
  float acc[4][4];
#pragma unroll
  for (int i = 0; i < 4; ++i)
#pragma unroll
    for (int j = 0; j < 4; ++j) acc[i][j] = 0.f;
  for (int dd = 0; dd < 128; ++dd) {
    f32x4 bv = *(const f32x4*)(&wm[dd * 64 + e0]);
#pragma unroll
    for (int i = 0; i < 4; ++i) {
      float a = wt[(dl + i) * 128 + dd];
#pragma unroll
      for (int j = 0; j < 4; ++j) acc[i][j] += a * bv[j];
    }
  }
  float sc = p ? 1.0f : QSCALE;
  int outcol0 = p * 4096 + head * 128 + eh * 64 + e0;
#pragma unroll
  for (int j = 0; j < 4; ++j) {
    ushort4v o;
#pragma unroll
    for (int i = 0; i < 4; ++i) o[i] = f2bf(acc[i][j] * sc);
    *(ushort4v*)(&WbT[(size_t)(outcol0 + j) * DM + d0 + dl]) = o;
  }
}

// ---------------- folded bias ----------------
__global__ void bias_kernel(const float* __restrict__ bqkv, const float* __restrict__ Wq,
                            const float* __restrict__ bq, const float* __restrict__ Wv,
                            const float* __restrict__ bv, float* __restrict__ biasf) {
  int col = blockIdx.x * 256 + threadIdx.x;
  if (col >= ND) return;
  float v;
  if (col < 2048) {
    int g = col >> 9, e = col & 127, base = col & ~127;
    float s = 0.f;
    for (int dd = 0; dd < 128; ++dd) s += bqkv[base + dd] * Wq[g * 16384 + dd * 128 + e];
    v = (s + bq[g * 128 + e]) * QSCALE;
  } else if (col < 4096) {
    v = bqkv[col];
  } else {
    int cv = col - 4096;
    int g = cv >> 9, e = cv & 127, base = col & ~127;
    float s = 0.f;
    for (int dd = 0; dd < 128; ++dd) s += bqkv[base + dd] * Wv[g * 16384 + dd * 128 + e];
    v = s + bv[g * 128 + e];
  }
  biasf[col] = v;
}

// ---- main GEMM: [4096,2048] x [2048,6144] bf16 ----
// BM=256 BN=128 BK=64, 512 thr (8 waves 4Mx2N), dbuf LDS 96KB,
// T2 xor-swizzle (both-sides), T3/T4 counted vmcnt(6), T5 setprio.
__global__ __launch_bounds__(512, 2) void gemm_kernel(
    const unsigned short* __restrict__ A, const unsigned short* __restrict__ Bt,
    const float* __restrict__ biasf, unsigned short* __restrict__ Qb,
    unsigned short* __restrict__ Kb, unsigned short* __restrict__ Vt) {
  extern __shared__ char lds[];               // 2 x (A 32KB | B 16KB)
  int bid = blockIdx.x;                       // 768
  int swz = (bid & 7) * 96 + (bid >> 3);      // XCD-aware (768 % 8 == 0)
  int bm = swz & 15, bn = swz >> 4;           // 16 x 48 tiles
  int m0 = bm * 256, n0 = bn * 128;
  int tid = threadIdx.x;
  int wid = tid >> 6, lane = tid & 63;
  int ln = lane & 15, hi = lane >> 4;
  int wr = wid >> 1, wc = wid & 1;            // wave tile 64x64

  // staging: 6 gload_lds/thread/tile; linear LDS dest, inverse-swizzled source
  int soff[6];
#pragma unroll
  for (int j = 0; j < 6; ++j) {
    int d = (j < 4 ? j * 8192 : (j - 4) * 8192) + tid * 16;  // linear byte in region
    int row = d >> 7;
    int p = d ^ ((row & 7) << 4);
    int kof = (p & 127) >> 1;
    soff[j] = (j < 4 ? (m0 + row) : (n0 + row)) * DM + kof;
  }
  auto stage = [&](int buf, int kel) {
#pragma unroll
    for (int j = 0; j < 6; ++j) {
      const unsigned short* s = (j < 4 ? A : Bt) + soff[j] + kel;
      char* dlds = lds + buf * 49152 +
                   (j < 4 ? j * 8192 : 32768 + (j - 4) * 8192) + wid * 1024;
      __builtin_amdgcn_global_load_lds(
          (const __attribute__((address_space(1))) void*)s,
          (__attribute__((address_space(3))) void*)dlds, 16, 0, 0);
    }
  };

  f32x4 acc[4][4] = {};
  const int swzl = (ln & 7) << 4;
  int arow0 = wr * 64 + ln;
  int brow0 = wc * 64 + ln;

  stage(0, 0);
  stage(1, 64);
  asm volatile("s_waitcnt vmcnt(6)" ::: "memory");
  asm volatile("s_barrier" ::: "memory");

  for (int t = 0; t < 32; ++t) {
    char* base = lds + (t & 1) * 49152;
    short8 a0[4], b0[4], a1[4], b1[4];
#pragma unroll
    for (int mi = 0; mi < 4; ++mi)
      a0[mi] = *(const short8*)(base + (((arow0 + mi * 16) * 128 + hi * 16) ^ swzl));
#pragma unroll
    for (int ni = 0; ni < 4; ++ni)
      b0[ni] = *(const short8*)(base + 32768 + (((brow0 + ni * 16) * 128 + hi * 16) ^ swzl));
    __builtin_amdgcn_s_setprio(1);
#pragma unroll
    for (int mi = 0; mi < 4; ++mi)
#pragma unroll
      for (int ni = 0; ni < 4; ++ni)
        acc[mi][ni] = MFMA(a0[mi], b0[ni], acc[mi][ni]);
    __builtin_amdgcn_s_setprio(0);
#pragma unroll
    for (int mi = 0; mi < 4; ++mi)
      a1[mi] = *(const short8*)(base + (((arow0 + mi * 16) * 128 + 64 + hi * 16) ^ swzl));
#pragma unroll
    for (int ni = 0; ni < 4; ++ni)
      b1[ni] = *(const short8*)(base + 32768 + (((brow0 + ni * 16) * 128 + 64 + hi * 16) ^ swzl));
    asm volatile("s_waitcnt lgkmcnt(0)" ::: "memory");
    asm volatile("s_barrier" ::: "memory");          // #1: all reads of this buf done
    if (t < 30) stage(t & 1, (t + 2) * 64);          // prefetch t+2 (hidden under kk1 MFMAs)
    __builtin_amdgcn_s_setprio(1);
#pragma unroll
    for (int mi = 0; mi < 4; ++mi)
#pragma unroll
      for (int ni = 0; ni < 4; ++ni)
        acc[mi][ni] = MFMA(a1[mi], b1[ni], acc[mi][ni]);
    __builtin_amdgcn_s_setprio(0);
    if (t < 30) {
      asm volatile("s_waitcnt vmcnt(6)" ::: "memory");   // t+1 resident, t+2 in flight
    } else if (t == 30) {
      asm volatile("s_waitcnt vmcnt(0)" ::: "memory");   // drain last tile
    }
    if (t < 31) asm volatile("s_barrier" ::: "memory");  // #2
  }

  int part = n0 >> 11;                 // 0=Q 1=K 2=V (uniform per block)
  int head = (n0 >> 7) & 15;
  int batch = m0 >> 11;
  int hbuf = batch * 16 + head;
#pragma unroll
  for (int ni = 0; ni < 4; ++ni) {
    int dcol = wc * 64 + ni * 16 + ln;
    float bsv = biasf[n0 + dcol];
#pragma unroll
    for (int mi = 0; mi < 4; ++mi) {
      int srow = (m0 & 2047) + wr * 64 + mi * 16 + hi * 4;
      f32x4 v = acc[mi][ni];
      if (part == 2) {  // V: store transposed [head][d][s]
        ushort4v o = {f2bf(v[0] + bsv), f2bf(v[1] + bsv), f2bf(v[2] + bsv), f2bf(v[3] + bsv)};
        *(ushort4v*)(&Vt[(size_t)(hbuf * 128 + dcol) * SEQ + srow]) = o;
      } else {          // Q / K: [head][s][d]
        unsigned short* dst = (part ? Kb : Qb) + ((size_t)hbuf * SEQ + srow) * HD + dcol;
        dst[0] = f2bf(v[0] + bsv);
        dst[HD] = f2bf(v[1] + bsv);
        dst[2 * HD] = f2bf(v[2] + bsv);
        dst[3 * HD] = f2bf(v[3] + bsv);
      }
    }
  }
}

// ---------------- flash attention with post-softmax mask ----------------
__global__ __launch_bounds__(256, 2) void attn_kernel(
    const unsigned short* __restrict__ Qb, const unsigned short* __restrict__ Kb,
    const unsigned short* __restrict__ Vt, const unsigned short* __restrict__ Mb,
    float* __restrict__ out) {
  __shared__ unsigned short Ks[64 * 128];   // [key][d]   swizzled
  __shared__ unsigned short Vs[128 * 64];   // [d][key]   swizzled
  __shared__ unsigned short Ms[128 * 64];   // [q][key]   bf16 mask, swizzled
  __shared__ unsigned short Ps[4][32 * 64]; // per-wave P [q][key], swizzled
  int bx = blockIdx.x;      // 512 = hb*16 + qtile
  int hb = bx >> 4;
  int q0 = (bx & 15) * 128;
  int b = hb >> 4, head = hb & 15;
  int tid = threadIdx.x, w = tid >> 6, l = tid & 63;
  int ln = l & 15, hi = l >> 4;
  const unsigned short* Qh = Qb + ((size_t)hb * SEQ + q0 + w * 32) * HD;
  const unsigned short* Kh = Kb + (size_t)hb * SEQ * HD;
  const unsigned short* Vh = Vt + (size_t)hb * HD * SEQ;
  char* KsB = (char*)(&Ks[0]);
  char* VsB = (char*)(&Vs[0]);
  char* MsB = (char*)(&Ms[0]);
  char* PwB = (char*)(&Ps[w][0]);

  short8 qf[2][4];  // Q rows (q = qb*16+ln), pre-scaled by scale*log2e in GEMM
#pragma unroll
  for (int qb = 0; qb < 2; ++qb)
#pragma unroll
    for (int kk = 0; kk < 4; ++kk)
      qf[qb][kk] = *(const short8*)(Qh + (qb * 16 + ln) * HD + kk * 32 + hi * 8);

  f32x4 acc[8][2] = {};
  float mrun[2] = {-1e30f, -1e30f}, Zrun[2] = {0.f, 0.f};

  for (int t = 0; t < 32; ++t) {
    int k0 = t * 64;
    __syncthreads();
    {  // stage K tile [64][128]
      int row = tid >> 2, seg = (tid & 3) * 64;
      const unsigned short* src = Kh + (size_t)(k0 + row) * HD + (seg >> 1);
      short8 tv[4];
#pragma unroll
      for (int j = 0; j < 4; ++j) tv[j] = *(const short8*)(src + j * 8);
#pragma unroll
      for (int j = 0; j < 4; ++j)
        *(short8*)(KsB + ((row * 256 + seg + j * 16) ^ ((row & 7) << 4))) = tv[j];
    }
    {  // stage V^T tile [128][64]
      int row = tid >> 1, seg = (tid & 1) * 64;
      const unsigned short* src = Vh + (size_t)row * SEQ + k0 + (seg >> 1);
      short8 tv[4];
#pragma unroll
      for (int j = 0; j < 4; ++j) tv[j] = *(const short8*)(src + j * 8);
#pragma unroll
      for (int j = 0; j < 4; ++j)
        *(short8*)(VsB + ((row * 128 + seg + j * 16) ^ ((row & 7) << 4))) = tv[j];
    }
    {  // stage mask tile [128][64]
      int row = tid >> 1, seg = (tid & 1) * 64;
      const unsigned short* src = Mb + (size_t)(q0 + row) * SEQ + k0 + (seg >> 1);
      short8 tv[4];
#pragma unroll
      for (int j = 0; j < 4; ++j) tv[j] = *(const short8*)(src + j * 8);
#pragma unroll
      for (int j = 0; j < 4; ++j)
        *(short8*)(MsB + ((row * 128 + seg + j * 16) ^ ((row & 7) << 4))) = tv[j];
    }
    __syncthreads();

    // S^T = K · Q^T  (rows=key lane-local -> cheap softmax)
    f32x4 sAcc[4][2] = {};
#pragma unroll
    for (int kk = 0; kk < 4; ++kk) {
#pragma unroll
      for (int mb = 0; mb < 4; ++mb) {
        int key = mb * 16 + ln;
        short8 kf = *(const short8*)(KsB + ((key * 256 + kk * 64 + hi * 16) ^ ((key & 7) << 4)));
        sAcc[mb][0] = MFMA(kf, qf[0][kk], sAcc[mb][0]);
        sAcc[mb][1] = MFMA(kf, qf[1][kk], sAcc[mb][1]);
      }
    }

    // online softmax (exp2 domain; Z unmasked, numerator masked)
#pragma unroll
    for (int qb = 0; qb < 2; ++qb) {
      float tm = -1e30f;
#pragma unroll
      for (int mb = 0; mb < 4; ++mb)
#pragma unroll
        for (int r = 0; r < 4; ++r) tm = fmaxf(tm, sAcc[mb][qb][r]);
      tm = fmaxf(tm, __shfl_xor(tm, 16));
      tm = fmaxf(tm, __shfl_xor(tm, 32));
      float mn = fmaxf(mrun[qb], tm);
      float al = __builtin_amdgcn_exp2f(mrun[qb] - mn);
      mrun[qb] = mn;
      float ts = 0.f;
      int qrow = w * 32 + qb * 16 + ln;
      int swzm = (qrow & 7) << 4;
      int swzp = (ln & 7) << 4;
#pragma unroll
      for (int mb = 0; mb < 4; ++mb) {
        u64 mk = *(const u64*)(MsB + ((qrow * 128 + mb * 32 + hi * 8) ^ swzm));
        u64 pk = 0;
#pragma unroll
        for (int r = 0; r < 4; ++r) {
          float p = __builtin_amdgcn_exp2f(sAcc[mb][qb][r] - mn);
          ts += p;
          float pm = p * bf2f((unsigned short)(mk >> (16 * r)));
          pk |= ((u64)f2bf(pm)) << (16 * r);
        }
        *(u64*)(PwB + (((qb * 16 + ln) * 128 + mb * 32 + hi * 8) ^ swzp)) = pk;
      }
      ts += __shfl_xor(ts, 16);
      ts += __shfl_xor(ts, 32);
      Zrun[qb] = Zrun[qb] * al + ts;
#pragma unroll
      for (int db = 0; db < 8; ++db) acc[db][qb] *= al;
    }

    // out^T += V^T · P^T   (A = V^T frags, B = P row-major frags)
#pragma unroll
    for (int kv = 0; kv < 2; ++kv) {
      short8 pf[2];
#pragma unroll
      for (int qb = 0; qb < 2; ++qb)
        pf[qb] = *(const short8*)(PwB + (((qb * 16 + ln) * 128 + kv * 64 + hi * 16) ^ ((ln & 7) << 4)));
#pragma unroll
      for (int db = 0; db < 8; ++db) {
        int d = db * 16 + ln;
        short8 vf = *(const short8*)(VsB + ((d * 128 + kv * 64 + hi * 16) ^ ((d & 7) << 4)));
        acc[db][0] = MFMA(vf, pf[0], acc[db][0]);
        acc[db][1] = MFMA(vf, pf[1], acc[db][1]);
      }
    }
  }

  // epilogue: out[b][s][head*128+d] = acc/Z   (f32, coalesced 64B lines)
#pragma unroll
  for (int qb = 0; qb < 2; ++qb) {
    float rz = 1.0f / Zrun[qb];
    int srow = q0 + w * 32 + qb * 16 + ln;
    float* dst = out + ((size_t)(b * SEQ + srow)) * DM + head * HD + hi * 4;
#pragma unroll
    for (int db = 0; db < 8; ++db) {
      f32x4 o;
#pragma unroll
      for (int r = 0; r < 4; ++r) o[r] = acc[db][qb][r] * rz;
      *(f32x4*)(dst + db * 16) = o;
    }
  }
}

extern "C" void kernel_launch(void* const* d_in, const int* in_sizes, int n_in,
                              void* d_out, int out_size, void* d_ws, size_t ws_size,
                              hipStream_t stream) {
  (void)in_sizes; (void)n_in; (void)out_size; (void)ws_size;
  const float* x    = (const float*)d_in[0];
  const float* mask = (const float*)d_in[1];
  const float* Wqkv = (const float*)d_in[2];
  const float* bqkv = (const float*)d_in[3];
  const float* Wq   = (const float*)d_in[4];
  const float* bq   = (const float*)d_in[5];
  const float* Wv   = (const float*)d_in[6];
  const float* bv   = (const float*)d_in[7];
  float* out = (float*)d_out;
  char* ws = (char*)d_ws;

  unsigned short* xb    = (unsigned short*)(ws);              // 16.8 MB
  unsigned short* maskb = (unsigned short*)(ws + 16777216);   // 8.4 MB
  unsigned short* WbT   = (unsigned short*)(ws + 25165824);   // 25.2 MB
  float*          biasf = (float*)(ws + 50331648);            // 24 KB
  unsigned short* Qb    = (unsigned short*)(ws + 50356224);   // 16.8 MB
  unsigned short* Kb    = (unsigned short*)(ws + 67133440);   // 16.8 MB
  unsigned short* Vt    = (unsigned short*)(ws + 83910656);   // 16.8 MB

  hipFuncSetAttribute((const void*)gemm_kernel,
                      hipFuncAttributeMaxDynamicSharedMemorySize, 98304);

  cvt_bf16_kernel<<<2048, 256, 0, stream>>>(x, xb, 2097152);
  cvt_bf16_kernel<<<1024, 256, 0, stream>>>(mask, maskb, 1048576);
  transk_kernel<<<1024, 256, 0, stream>>>(Wqkv, WbT);
  fold_kernel<<<2048, 256, 0, stream>>>(Wqkv, Wq, Wv, WbT);
  bias_kernel<<<24, 256, 0, stream>>>(bqkv, Wq, bq, Wv, bv, biasf);
  gemm_kernel<<<768, 512, 98304, stream>>>(xb, WbT, biasf, Qb, Kb, Vt);
  attn_kernel<<<512, 256, 0, stream>>>(Qb, Kb, Vt, maskb, out);
}